// Round 15
// baseline (203.840 us; speedup 1.0000x reference)
//
#include <hip/hip_runtime.h>

#define NG 50000
#define NCT 64
#define NREF 16
#define NS 1024
#define N0 (NCT * NG)              // 3,200,000  (y0/y1/y2 length)

// d_out layout: out [NS*NG] | y0 [N0] | y1 [N0] | y2 [N0]
#define OFF_Y0 ((size_t)NS * NG)   // 51,200,000
#define OFF_Y1 (OFF_Y0 + N0)
#define OFF_Y2 (OFF_Y1 + N0)

typedef __attribute__((ext_vector_type(8))) short bf16x8;
typedef __attribute__((ext_vector_type(4))) float f32x4;
typedef __attribute__((ext_vector_type(4))) unsigned short u16x4;

__device__ __forceinline__ unsigned short f2bf(float f) {
    union { float f; unsigned u; } v; v.f = f;
    unsigned r = v.u + 0x7fff + ((v.u >> 16) & 1);   // RNE
    return (unsigned short)(r >> 16);
}
__device__ __forceinline__ float bf2f(unsigned short b) {
    union { float f; unsigned u; } v; v.u = ((unsigned)b) << 16;
    return v.f;
}

// ---------------- Kernel 1: RefComb * tile + slice-sum -> y0 ----------------
// (measured at HBM roofline: ~33 us, 6.6 TB/s)
__global__ __launch_bounds__(256) void k_y0(const float* __restrict__ x,
                                            const float* __restrict__ w_ref,
                                            float* __restrict__ y0) {
    __shared__ f32x4 wl[256];
    const int tid = threadIdx.x;
    wl[tid] = reinterpret_cast<const f32x4*>(w_ref)[tid];
    __syncthreads();
    const int row = tid & 63;
    const f32x4 w0 = wl[row * 4 + 0];
    const f32x4 w1 = wl[row * 4 + 1];
    const f32x4 w2 = wl[row * 4 + 2];
    const f32x4 w3 = wl[row * 4 + 3];
    const f32x4* x4 = reinterpret_cast<const f32x4*>(x);
    const size_t stride = (size_t)gridDim.x * 256;
    for (size_t j = (size_t)blockIdx.x * 256 + tid; j < (size_t)N0; j += stride) {
        const f32x4* xp = x4 + j * 4;
        f32x4 a = __builtin_nontemporal_load(xp + 0);
        f32x4 b = __builtin_nontemporal_load(xp + 1);
        f32x4 c = __builtin_nontemporal_load(xp + 2);
        f32x4 d = __builtin_nontemporal_load(xp + 3);
        float s = a.x * w0.x + a.y * w0.y + a.z * w0.z + a.w * w0.w
                + b.x * w1.x + b.y * w1.y + b.z * w1.z + b.w * w1.w
                + c.x * w2.x + c.y * w2.y + c.z * w2.z + c.w * w2.w
                + d.x * w3.x + d.y * w3.y + d.z * w3.z + d.w * w3.w;
        y0[j] = s;                             // plain store: keep y0 cache-resident
    }
}

// ------- Kernel 1b: pre-convert cw (1024x64 fp32) to bf16 hi/lo planes in ws -------
__global__ __launch_bounds__(256) void k_cw(const float* __restrict__ cw,
                                            unsigned short* __restrict__ cwhi,
                                            unsigned short* __restrict__ cwlo) {
    int i = (blockIdx.x * 256 + threadIdx.x) * 4;    // 64 blocks cover 65536
    f32x4 v = *reinterpret_cast<const f32x4*>(cw + i);
    u16x4 h, l;
#pragma unroll
    for (int e = 0; e < 4; ++e) {
        unsigned short hh = f2bf(v[e]);
        h[e] = hh;
        l[e] = f2bf(v[e] - bf2f(hh));
    }
    *reinterpret_cast<u16x4*>(cwhi + i) = h;
    *reinterpret_cast<u16x4*>(cwlo + i) = l;
}

// ------- Kernel 2: gather + scale + stretch -> y1, y2 (high-MLP, latency regime) -------
// ~12 waves/CU x 16 outstanding loads: latency-bound throughput ~130 G loads/s.
__global__ __launch_bounds__(256) void k_gather2(const float* __restrict__ y0,
                                                 const int* __restrict__ idx,
                                                 const float* __restrict__ w_ct,
                                                 const float* __restrict__ w_stretch,
                                                 float* __restrict__ y1,
                                                 float* __restrict__ y2) {
    __shared__ float T[64 * 65];                     // [c][g], +1 pad
    const int tid = threadIdx.x;
    const int g0 = blockIdx.x * 64;

    int ids[16];
#pragma unroll
    for (int k = 0; k < 16; ++k) {
        int lin = k * 256 + tid;
        int c = lin >> 6, gl = lin & 63;
        int gc = min(g0 + gl, NG - 1);               // clamp; tail masked at stores
        ids[k] = idx[c * NG + gc];
    }
    float vals[16];
#pragma unroll
    for (int k = 0; k < 16; ++k) vals[k] = y0[ids[k]];
#pragma unroll
    for (int k = 0; k < 16; ++k) {
        int lin = k * 256 + tid;
        int c = lin >> 6, gl = lin & 63;
        T[c * 65 + gl] = vals[k];
    }
    __syncthreads();

#pragma unroll
    for (int k = 0; k < 16; ++k) {
        int lin = k * 256 + tid;
        int gl = lin >> 6, c = lin & 63;             // consecutive lanes -> consecutive c
        int g = g0 + gl;
        if (g < NG) {
            float t = T[c * 65 + gl];
            float v1 = t * w_ct[c];
            float v2 = v1 * w_stretch[g];            // wave-uniform
            size_t o = (size_t)g * 64 + c;
            __builtin_nontemporal_store(v1, y1 + o);
            __builtin_nontemporal_store(v2, y2 + o);
        }
    }
}

// ------- Kernel 3: MFMA conv  out[s,g] = sum_c y2[g,c]*cw[s,c] -------
// LDS-free, barrier-free, write-bound. A: y2 NT fp32 -> hi/lo split ONCE per block.
// B: 16B bf16x8 loads from L2-hot preconverted planes (zero per-chunk VALU).
// acc += Ah*Bh + Ah*Bl + Al*Bh. D (m89): col=lane&15 -> s, row=(lane>>4)*4+reg -> g.
#define STILE 128
template<bool PRECONV>
__global__ __launch_bounds__(256) void k_conv2(const float* __restrict__ y2,
                                               const float* __restrict__ cw,
                                               const unsigned short* __restrict__ cwhi,
                                               const unsigned short* __restrict__ cwlo,
                                               float* __restrict__ out) {
    const int tid  = threadIdx.x;
    const int g0   = blockIdx.x * 64;
    const int lane = tid & 63;
    const int wid  = tid >> 6;
    const int l15  = lane & 15;
    const int l4   = lane >> 4;
    const int nb   = wid * 32;

    // A fragments: NT fp32 load + one-time hi/lo split (row clamped for tail block)
    bf16x8 Ah[4][2], Al[4][2];
#pragma unroll
    for (int m = 0; m < 4; ++m) {
        size_t row = (size_t)min(g0 + m * 16 + l15, NG - 1) * 64;
#pragma unroll
        for (int ks = 0; ks < 2; ++ks) {
            int koff = ks * 32 + l4 * 8;
            f32x4 va = __builtin_nontemporal_load(reinterpret_cast<const f32x4*>(y2 + row + koff));
            f32x4 vb = __builtin_nontemporal_load(reinterpret_cast<const f32x4*>(y2 + row + koff + 4));
#pragma unroll
            for (int e = 0; e < 4; ++e) {
                unsigned short h = f2bf(va[e]);
                Ah[m][ks][e] = (short)h;
                Al[m][ks][e] = (short)f2bf(va[e] - bf2f(h));
                h = f2bf(vb[e]);
                Ah[m][ks][e + 4] = (short)h;
                Al[m][ks][e + 4] = (short)f2bf(vb[e] - bf2f(h));
            }
        }
    }

    for (int s0 = 0; s0 < NS; s0 += STILE) {
        f32x4 acc[4][2];
#pragma unroll
        for (int m = 0; m < 4; ++m)
#pragma unroll
            for (int n = 0; n < 2; ++n) acc[m][n] = (f32x4){0.f, 0.f, 0.f, 0.f};

#pragma unroll
        for (int n = 0; n < 2; ++n) {
            const size_t srow = (size_t)(s0 + nb + n * 16 + l15) * 64;
            bf16x8 Bh[2], Bl[2];
#pragma unroll
            for (int ks = 0; ks < 2; ++ks) {
                int koff = ks * 32 + l4 * 8;
                if (PRECONV) {
                    Bh[ks] = *reinterpret_cast<const bf16x8*>(cwhi + srow + koff);
                    Bl[ks] = *reinterpret_cast<const bf16x8*>(cwlo + srow + koff);
                } else {
                    f32x4 va = *reinterpret_cast<const f32x4*>(cw + srow + koff);
                    f32x4 vb = *reinterpret_cast<const f32x4*>(cw + srow + koff + 4);
#pragma unroll
                    for (int e = 0; e < 4; ++e) {
                        unsigned short h = f2bf(va[e]);
                        Bh[ks][e] = (short)h;
                        Bl[ks][e] = (short)f2bf(va[e] - bf2f(h));
                        h = f2bf(vb[e]);
                        Bh[ks][e + 4] = (short)h;
                        Bl[ks][e + 4] = (short)f2bf(vb[e] - bf2f(h));
                    }
                }
            }
#pragma unroll
            for (int m = 0; m < 4; ++m)
#pragma unroll
                for (int ks = 0; ks < 2; ++ks) {
                    acc[m][n] = __builtin_amdgcn_mfma_f32_16x16x32_bf16(Ah[m][ks], Bh[ks], acc[m][n], 0, 0, 0);
                    acc[m][n] = __builtin_amdgcn_mfma_f32_16x16x32_bf16(Ah[m][ks], Bl[ks], acc[m][n], 0, 0, 0);
                    acc[m][n] = __builtin_amdgcn_mfma_f32_16x16x32_bf16(Al[m][ks], Bh[ks], acc[m][n], 0, 0, 0);
                }
        }

#pragma unroll
        for (int m = 0; m < 4; ++m) {
            int g4 = g0 + m * 16 + l4 * 4;
            if (g4 < NG) {
#pragma unroll
                for (int n = 0; n < 2; ++n) {
                    int s = s0 + nb + n * 16 + l15;
                    __builtin_nontemporal_store(acc[m][n], reinterpret_cast<f32x4*>(out + (size_t)s * NG + g4));
                }
            }
        }
    }
}

extern "C" void kernel_launch(void* const* d_in, const int* in_sizes, int n_in,
                              void* d_out, int out_size, void* d_ws, size_t ws_size,
                              hipStream_t stream) {
    const float* x         = (const float*)d_in[0];
    const int*   idx       = (const int*)d_in[1];
    const float* w_ref     = (const float*)d_in[2];
    const float* w_ct      = (const float*)d_in[3];
    const float* w_stretch = (const float*)d_in[4];
    const float* conv_w    = (const float*)d_in[5];

    float* out = (float*)d_out;
    float* y0  = out + OFF_Y0;
    float* y1  = out + OFF_Y1;
    float* y2  = out + OFF_Y2;

    k_y0<<<2048, 256, 0, stream>>>(x, w_ref, y0);
    k_gather2<<<(NG + 63) / 64, 256, 0, stream>>>(y0, idx, w_ct, w_stretch, y1, y2);

    const size_t need = 2 * (size_t)NS * NCT * sizeof(unsigned short);   // 256 KB
    if (ws_size >= need) {
        unsigned short* cwhi = (unsigned short*)d_ws;
        unsigned short* cwlo = cwhi + (size_t)NS * NCT;
        k_cw<<<NS * NCT / 1024, 256, 0, stream>>>(conv_w, cwhi, cwlo);
        k_conv2<true><<<(NG + 63) / 64, 256, 0, stream>>>(y2, conv_w, cwhi, cwlo, out);
    } else {
        k_conv2<false><<<(NG + 63) / 64, 256, 0, stream>>>(y2, conv_w, nullptr, nullptr, out);
    }
}

// Round 16
// 172.529 us; speedup vs baseline: 1.1815x; 1.1815x over previous
//
#include <hip/hip_runtime.h>
#include <hip/hip_fp16.h>

#define NG 50000
#define NCT 64
#define NREF 16
#define NS 1024
#define N0 (NCT * NG)              // 3,200,000  (y0/y1/y2 length)

// d_out layout: out [NS*NG] | y0 [N0] | y1 [N0] | y2 [N0]
#define OFF_Y0 ((size_t)NS * NG)   // 51,200,000
#define OFF_Y1 (OFF_Y0 + N0)
#define OFF_Y2 (OFF_Y1 + N0)

typedef __attribute__((ext_vector_type(8))) short bf16x8;
typedef __attribute__((ext_vector_type(4))) float f32x4;

__device__ __forceinline__ unsigned short f2bf(float f) {
    union { float f; unsigned u; } v; v.f = f;
    unsigned r = v.u + 0x7fff + ((v.u >> 16) & 1);   // RNE
    return (unsigned short)(r >> 16);
}
__device__ __forceinline__ float bf2f(unsigned short b) {
    union { float f; unsigned u; } v; v.u = ((unsigned)b) << 16;
    return v.f;
}

// ---------------- Kernel 1: RefComb * tile + slice-sum -> y0 (+ fp16 shadow) ----------------
// (measured at HBM roofline: ~33 us, 6.6 TB/s; +6.4 MB fp16 shadow for the gather)
template<bool H16>
__global__ __launch_bounds__(256) void k_y0(const float* __restrict__ x,
                                            const float* __restrict__ w_ref,
                                            float* __restrict__ y0,
                                            __half* __restrict__ y0h) {
    __shared__ f32x4 wl[256];
    const int tid = threadIdx.x;
    wl[tid] = reinterpret_cast<const f32x4*>(w_ref)[tid];
    __syncthreads();
    const int row = tid & 63;
    const f32x4 w0 = wl[row * 4 + 0];
    const f32x4 w1 = wl[row * 4 + 1];
    const f32x4 w2 = wl[row * 4 + 2];
    const f32x4 w3 = wl[row * 4 + 3];
    const f32x4* x4 = reinterpret_cast<const f32x4*>(x);
    const size_t stride = (size_t)gridDim.x * 256;
    for (size_t j = (size_t)blockIdx.x * 256 + tid; j < (size_t)N0; j += stride) {
        const f32x4* xp = x4 + j * 4;
        f32x4 a = __builtin_nontemporal_load(xp + 0);
        f32x4 b = __builtin_nontemporal_load(xp + 1);
        f32x4 c = __builtin_nontemporal_load(xp + 2);
        f32x4 d = __builtin_nontemporal_load(xp + 3);
        float s = a.x * w0.x + a.y * w0.y + a.z * w0.z + a.w * w0.w
                + b.x * w1.x + b.y * w1.y + b.z * w1.z + b.w * w1.w
                + c.x * w2.x + c.y * w2.y + c.z * w2.z + c.w * w2.w
                + d.x * w3.x + d.y * w3.y + d.z * w3.z + d.w * w3.w;
        y0[j] = s;                               // fp32 output (streamed, not re-read)
        if (H16) y0h[j] = __float2half(s);       // 6.4 MB shadow: the gather target
    }
}

// ------- Kernel 2: producer/consumer fused gather + scale + stretch + MFMA conv -------
// EXACTLY r12's measured kernel (146 us) except producers gather from the fp16
// shadow (6.4 MB footprint -> per-XCD L2 hit rate ~2x, miss count ~halved).
// 512 threads: waves 0-3 producers, waves 4-7 consumers; two 32-gene halves,
// double-buffered bf16 hi/lo A-planes; consumer B from cw with in-reg hi/lo split.
// MFMA: acc += Ah*Bh + Ah*Bl + Al*Bh. D (m89): col=lane&15 -> s, row=(lane>>4)*4+reg -> g.
template<bool H16>
__global__ __launch_bounds__(512) void k_pc(const float* __restrict__ y0,
                                            const __half* __restrict__ y0h,
                                            const int* __restrict__ idx,
                                            const float* __restrict__ w_ct,
                                            const float* __restrict__ w_stretch,
                                            const float* __restrict__ cw,
                                            float* __restrict__ y1,
                                            float* __restrict__ y2,
                                            float* __restrict__ out) {
    __shared__ float T[4][64 * 9];                   // per-producer-wave transpose
    __shared__ unsigned short Phi[2][32 * 72];       // A-planes hi, double-buffered
    __shared__ unsigned short Plo[2][32 * 72];       // A-planes lo

    const int tid  = threadIdx.x;
    const int lane = tid & 63;
    const int wid  = tid >> 6;                       // 0..7
    const int g0   = blockIdx.x * 64;

    if (wid < 4) {
        // ================= producers =================
        const int p = wid;                           // genes p*8..p*8+7 of each half
        const float wct = w_ct[lane];                // phase-B c == lane
        float* Tp = T[p];
        for (int h = 0; h < 2; ++h) {
            const int gbase = g0 + 32 * h + p * 8;
            int iids[8];
#pragma unroll
            for (int k = 0; k < 8; ++k) {
                int j = lane & 7;
                int c = (lane >> 3) + k * 8;
                int g = min(gbase + j, NG - 1);      // clamp; garbage masked at stores
                iids[k] = idx[c * NG + g];
            }
            float vals[8];
#pragma unroll
            for (int k = 0; k < 8; ++k) {
                if (H16) vals[k] = __half2float(y0h[iids[k]]);   // 6.4 MB footprint
                else     vals[k] = y0[iids[k]];
            }
#pragma unroll
            for (int k = 0; k < 8; ++k) {
                int j = lane & 7;
                int c = (lane >> 3) + k * 8;
                Tp[c * 9 + j] = vals[k];
            }
#pragma unroll
            for (int j = 0; j < 8; ++j) {
                int g = gbase + j;
                float t = Tp[lane * 9 + j];          // stride-9: conflict-free
                float v1 = t * wct;
                float v2 = v1 * w_stretch[min(g, NG - 1)];  // wave-uniform
                int base = (p * 8 + j) * 72 + lane;
                unsigned short hh = f2bf(v2);
                Phi[h][base] = hh;
                Plo[h][base] = f2bf(v2 - bf2f(hh));
                if (g < NG) {
                    size_t o = (size_t)g * 64 + lane;   // coalesced 256B
                    __builtin_nontemporal_store(v1, y1 + o);
                    __builtin_nontemporal_store(v2, y2 + o);
                }
            }
            __syncthreads();                         // h=0: bar1, h=1: bar2
        }
    } else {
        // ================= consumers =================
        const int cwv = wid - 4;                     // 0..3 -> 32-sample strip
        const int l15 = lane & 15;
        const int l4  = lane >> 4;
        __syncthreads();                             // bar1: planes(0) ready
        for (int h = 0; h < 2; ++h) {
            bf16x8 Ah[2][2], Al[2][2];
#pragma unroll
            for (int m = 0; m < 2; ++m) {
                int grow = m * 16 + l15;
#pragma unroll
                for (int ks = 0; ks < 2; ++ks) {
                    int koff = ks * 32 + l4 * 8;
                    Ah[m][ks] = *reinterpret_cast<const bf16x8*>(&Phi[h][grow * 72 + koff]);
                    Al[m][ks] = *reinterpret_cast<const bf16x8*>(&Plo[h][grow * 72 + koff]);
                }
            }
            const int gh = g0 + 32 * h;
            for (int s0 = 0; s0 < NS; s0 += 128) {
                f32x4 acc[2][2];
#pragma unroll
                for (int m = 0; m < 2; ++m)
#pragma unroll
                    for (int n = 0; n < 2; ++n) acc[m][n] = (f32x4){0.f, 0.f, 0.f, 0.f};
#pragma unroll
                for (int n = 0; n < 2; ++n) {
                    const size_t srow = (size_t)(s0 + cwv * 32 + n * 16 + l15) * 64;
                    bf16x8 Bh[2], Bl[2];
#pragma unroll
                    for (int ks = 0; ks < 2; ++ks) {
                        int koff = ks * 32 + l4 * 8;
                        f32x4 va = *reinterpret_cast<const f32x4*>(cw + srow + koff);
                        f32x4 vb = *reinterpret_cast<const f32x4*>(cw + srow + koff + 4);
#pragma unroll
                        for (int e = 0; e < 4; ++e) {
                            unsigned short hv = f2bf(va[e]);
                            Bh[ks][e] = (short)hv;
                            Bl[ks][e] = (short)f2bf(va[e] - bf2f(hv));
                            hv = f2bf(vb[e]);
                            Bh[ks][e + 4] = (short)hv;
                            Bl[ks][e + 4] = (short)f2bf(vb[e] - bf2f(hv));
                        }
                    }
#pragma unroll
                    for (int m = 0; m < 2; ++m)
#pragma unroll
                        for (int ks = 0; ks < 2; ++ks) {
                            acc[m][n] = __builtin_amdgcn_mfma_f32_16x16x32_bf16(Ah[m][ks], Bh[ks], acc[m][n], 0, 0, 0);
                            acc[m][n] = __builtin_amdgcn_mfma_f32_16x16x32_bf16(Ah[m][ks], Bl[ks], acc[m][n], 0, 0, 0);
                            acc[m][n] = __builtin_amdgcn_mfma_f32_16x16x32_bf16(Al[m][ks], Bh[ks], acc[m][n], 0, 0, 0);
                        }
                }
#pragma unroll
                for (int m = 0; m < 2; ++m) {
                    int g4 = gh + m * 16 + l4 * 4;
                    if (g4 < NG) {
#pragma unroll
                        for (int n = 0; n < 2; ++n) {
                            int s = s0 + cwv * 32 + n * 16 + l15;
                            __builtin_nontemporal_store(acc[m][n], reinterpret_cast<f32x4*>(out + (size_t)s * NG + g4));
                        }
                    }
                }
            }
            if (h == 0) __syncthreads();             // bar2: planes(1) ready
        }
    }
}

extern "C" void kernel_launch(void* const* d_in, const int* in_sizes, int n_in,
                              void* d_out, int out_size, void* d_ws, size_t ws_size,
                              hipStream_t stream) {
    const float* x         = (const float*)d_in[0];
    const int*   idx       = (const int*)d_in[1];
    const float* w_ref     = (const float*)d_in[2];
    const float* w_ct      = (const float*)d_in[3];
    const float* w_stretch = (const float*)d_in[4];
    const float* conv_w    = (const float*)d_in[5];

    float* out = (float*)d_out;
    float* y0  = out + OFF_Y0;
    float* y1  = out + OFF_Y1;
    float* y2  = out + OFF_Y2;

    const bool h16 = (ws_size >= (size_t)N0 * sizeof(__half));   // 6.4 MB
    __half* y0h = (__half*)d_ws;

    if (h16) {
        k_y0<true><<<2048, 256, 0, stream>>>(x, w_ref, y0, y0h);
        k_pc<true><<<(NG + 63) / 64, 512, 0, stream>>>(y0, y0h, idx, w_ct, w_stretch,
                                                       conv_w, y1, y2, out);
    } else {
        k_y0<false><<<2048, 256, 0, stream>>>(x, w_ref, y0, nullptr);
        k_pc<false><<<(NG + 63) / 64, 512, 0, stream>>>(y0, nullptr, idx, w_ct, w_stretch,
                                                        conv_w, y1, y2, out);
    }
}